// Round 3
// baseline (229.006 us; speedup 1.0000x reference)
//
#include <hip/hip_runtime.h>
#include <hip/hip_bf16.h>

using bf16 = __hip_bfloat16;
typedef __attribute__((ext_vector_type(8))) short short8;   // 8 bf16 (4 VGPR)
typedef __attribute__((ext_vector_type(4))) short short4v;  // 4 bf16 (8 B)
typedef __attribute__((ext_vector_type(4))) float f32x4;

constexpr int BATCH = 32;
constexpr int INC = 3;
constexpr int OC = 64;
constexpr int HH = 64;
constexpr int WW = 64;
constexpr int KK = 5;
constexpr int HP = 32;
constexpr int WP = 32;
constexpr int NL = 16;
constexpr int LW = 128;
constexpr int OW = 100;

__device__ __forceinline__ short f2bs(float v) {
  bf16 h = __float2bfloat16(v);
  return *(short*)&h;
}

// 16B zero page: per-lane global source for halo/pad lanes of global_load_lds.
// Device globals are zero-initialized at module load.
__device__ alignas(16) short zero16[16];

// ---------------- routing scores (partial): conv(x, node_filter) -> 16-row-group max ------
// grid: 4 depths * 32 batch * 4 row-groups = 512 blocks, 256 threads
__global__ __launch_bounds__(256) void k_scores(
    const float* __restrict__ x, const float* __restrict__ nw,
    float* __restrict__ scores_p) {
  int bid = blockIdx.x;
  int d = bid & 3;
  int b = (bid >> 2) & 31;
  int g = bid >> 7;  // 0..3: rows 16g..16g+15
  int f = (2 << d) - 2;  // node filter index used at depth d: 0,2,6,14
  __shared__ float wsm[75];
  __shared__ float red[256];
  int t = threadIdx.x;
  if (t < 75) wsm[t] = nw[f * 75 + t];
  __syncthreads();
  float m = -3.0e38f;
  for (int p = g * 1024 + t; p < (g + 1) * 1024; p += 256) {
    int y = p >> 6, xx = p & 63;
    float s = 0.f;
    for (int ic = 0; ic < INC; ic++) {
      for (int ky = 0; ky < KK; ky++) {
        int yy = y + ky - 2;
        if (yy < 0 || yy >= HH) continue;
        const float* xr = x + ((b * INC + ic) * HH + yy) * WW;
        const float* wr = &wsm[(ic * KK + ky) * KK];
        for (int kx = 0; kx < KK; kx++) {
          int xc = xx + kx - 2;
          if (xc < 0 || xc >= WW) continue;
          s = fmaf(xr[xc], wr[kx], s);
        }
      }
    }
    m = fmaxf(m, s);
  }
  red[t] = m;
  __syncthreads();
  for (int s2 = 128; s2 > 0; s2 >>= 1) {
    if (t < s2) red[t] = fmaxf(red[t], red[t + s2]);
    __syncthreads();
  }
  if (t == 0) scores_p[(d * BATCH + b) * 4 + g] = red[0];
}

// ---------------- soft-routing mixture over the binary tree (folds 4 partial maxes) -------
__global__ void k_mix(const float* __restrict__ scores_p,
                      const float* __restrict__ nb, float* __restrict__ mix) {
  int t = threadIdx.x;
  int b = t >> 4, l = t & 15;
  float m = 1.f;
#pragma unroll
  for (int d = 0; d < 4; d++) {
    const float* sp = scores_p + (d * BATCH + b) * 4;
    float sc = fmaxf(fmaxf(sp[0], sp[1]), fmaxf(sp[2], sp[3]));
    int j = l >> (3 - d);
    int i = j >> 1;
    int bit = j & 1;
    float z = sc + nb[(1 << d) - 1 + i];
    float be = 1.f / (1.f + expf(-z));
    m *= bit ? be : (1.f - be);
  }
  mix[b * NL + l] = m;
}

// ---------------- merged weight prep ----------------
__global__ __launch_bounds__(256) void k_prep(
    const float* __restrict__ cw1, const float* __restrict__ cw2,
    short* __restrict__ wA, short* __restrict__ wT) {
  int idx = blockIdx.x * 256 + threadIdx.x;
  if (idx < 98304) {
    int k = idx % 96;
    int rem = idx / 96;  // l*64 + oc
    float v = (k < 75) ? cw1[(size_t)rem * 75 + k] : 0.f;
    wA[(size_t)rem * 96 + k] = f2bs(v);
  } else {
    int i2 = idx - 98304;  // < 204800
    int icq = i2 & 7;
    int oc = (i2 >> 3) & 63;
    int rem = i2 >> 9;  // l*25 + tap
    short8 v;
#pragma unroll
    for (int j = 0; j < 8; j++) {
      int ic = icq * 8 + j;
      int l = rem / 25, tap = rem % 25;
      v[j] = f2bs(cw2[((size_t)(l * OC + oc) * OC + ic) * 25 + tap]);
    }
    *(short8*)(wT + ((size_t)rem * OC + oc) * OC + icq * 8) = v;
  }
}

// ---------------- conv1 via im2col + MFMA + in-register maxpool/relu -> h1t ----------------
// (R8/R12 version verbatim — known-good on hardware)
__device__ __forceinline__ int slotbase(int col) {
  return col * 104 + 8 * ((-(col >> 1)) & 7);
}

__global__ __launch_bounds__(256) void k_conv1m(
    const float* __restrict__ x, const short* __restrict__ wA,
    short* __restrict__ h1t) {
  constexpr int BSZ = 64 * 104 + 64;
  constexpr int OTS = 72;
  __shared__ alignas(16) short Bm[2 * BSZ];
  __shared__ alignas(16) short ot[32 * OTS];
  int bid = blockIdx.x;
  int py = bid & 31;
  int b = bid >> 5;
  int t = threadIdx.x;
  int w = t >> 6, lane = t & 63;
  int n = lane & 15, q = lane >> 4;

  for (int i = t; i < BSZ; i += 256) ((int*)Bm)[i] = 0;
  __syncthreads();
  for (int i = t; i < 1200; i += 256) {
    int cg = i & 7;
    int kk = (i >> 3) % 75;
    int dy = (i >> 3) / 75;
    int ic = kk / 25, r25 = kk % 25;
    int ky = r25 / 5, kx = r25 % 5;
    int y = 2 * py + dy + ky - 2;
    const float* xr = x + ((size_t)(b * INC + ic) * HH + y) * WW;
    short* dst = Bm + dy * BSZ;
#pragma unroll
    for (int c8 = 0; c8 < 8; c8++) {
      int c = cg * 8 + c8;
      int cx = c + kx - 2;
      float v = 0.f;
      if (y >= 0 && y < HH && cx >= 0 && cx < WW) v = xr[cx];
      dst[slotbase(c) + kk] = f2bs(v);
    }
  }
  __syncthreads();

  short8 Acur[3], Anx[3];
#pragma unroll
  for (int ks = 0; ks < 3; ks++)
    Anx[ks] = *(const short8*)(wA + ((size_t)(w * 16 + n) * 96) + ks * 32 + q * 8);

  for (int l = 0; l < NL; l++) {
#pragma unroll
    for (int ks = 0; ks < 3; ks++) Acur[ks] = Anx[ks];
    if (l < NL - 1) {
#pragma unroll
      for (int ks = 0; ks < 3; ks++)
        Anx[ks] = *(const short8*)(wA + ((size_t)((l + 1) * OC + w * 16 + n) * 96) +
                                   ks * 32 + q * 8);
    }
    f32x4 acc[2][2][2];  // [dy][dx][half]
#pragma unroll
    for (int dy = 0; dy < 2; dy++)
#pragma unroll
      for (int dx = 0; dx < 2; dx++)
#pragma unroll
        for (int h = 0; h < 2; h++) acc[dy][dx][h] = f32x4{0.f, 0.f, 0.f, 0.f};

#pragma unroll
    for (int dy = 0; dy < 2; dy++)
#pragma unroll
      for (int dx = 0; dx < 2; dx++)
#pragma unroll
        for (int h = 0; h < 2; h++) {
          int col = 2 * (h * 16 + n) + dx;
          const short* bp = Bm + dy * BSZ + slotbase(col);
#pragma unroll
          for (int ks = 0; ks < 3; ks++) {
            short8 Bf = *(const short8*)(bp + ks * 32 + q * 8);
            acc[dy][dx][h] = __builtin_amdgcn_mfma_f32_16x16x32_bf16(
                Acur[ks], Bf, acc[dy][dx][h], 0, 0, 0);
          }
        }

#pragma unroll
    for (int h = 0; h < 2; h++) {
      short4v sv;
#pragma unroll
      for (int r = 0; r < 4; r++) {
        float v = fmaxf(fmaxf(acc[0][0][h][r], acc[0][1][h][r]),
                        fmaxf(acc[1][0][h][r], acc[1][1][h][r]));
        sv[r] = f2bs(fmaxf(v, 0.f));
      }
      *(short4v*)(&ot[(h * 16 + n) * OTS + w * 16 + q * 4]) = sv;
    }
    __syncthreads();
    {
      int px = t >> 3, seg = t & 7;
      short8 v = *(const short8*)(&ot[px * OTS + seg * 8]);
      *(short8*)(h1t + ((size_t)(l * BATCH + b) * (HP * WP) + py * WP + px) * OC +
                 seg * 8) = v;
    }
    __syncthreads();
  }
}

// ---------------- conv2 via MFMA implicit GEMM + spatial max -> pfeat ----------------
// R15: (a) dy-fold — for each (chunk, dx) read each of the wave's 8 slab rows ONCE
// and scatter MFMAs into acc[j-dy]; B-reads drop 2.5x (1600 -> 640 per block).
// A-frags for 5 taps live concurrently (Acur[5][4], 80 VGPR).
// (b) staging via global_load_lds width=16: linear LDS dest (CS=32, slab = idx*16B),
// halo/pad lanes source from zero16 page. No reg round-trip, no ds_write pass.
__global__ __launch_bounds__(256, 2) void k_conv2m(
    const short* __restrict__ h1t, const short* __restrict__ wT,
    float* __restrict__ pfeat) {
  constexpr int CS2 = 32;          // shorts per col slot (64 B, no pad: linear)
  constexpr int RS2 = 36 * CS2;    // 1152 shorts = 2304 B per slab row
  __shared__ alignas(16) short hs[3072 * 8];  // 49152 B (20*2304=46080 used + pad)
  __shared__ alignas(16) float sred[4][64];
  int bid = blockIdx.x;
  int half = bid & 1;
  int b = (bid >> 1) & 31;
  int l = bid >> 6;
  int t = threadIdx.x;
  int w = t >> 6, lane = t & 63;
  int n = lane & 15, q = lane >> 4;
  int y0 = half * 16;
  const short* hg = h1t + (size_t)(l * BATCH + b) * (HP * WP) * OC;
  const short* wbase = wT + (size_t)l * 25 * OC * OC;

  f32x4 acc[4][8];  // [octile][pxt = rt*2 + colhalf], rt = local out row 0..3
#pragma unroll
  for (int i = 0; i < 4; i++)
#pragma unroll
    for (int j = 0; j < 8; j++) acc[i][j] = f32x4{0.f, 0.f, 0.f, 0.f};

  for (int chunk = 0; chunk < 2; chunk++) {
    __syncthreads();  // protect hs from previous chunk's readers
    // stage: 12 uniform iters x 256 thr = 3072 x 16B (2880 real + pad -> zero page)
#pragma unroll
    for (int i = 0; i < 12; i++) {
      int idx = i * 256 + t;            // 0..3071
      int icq = idx & 3;
      int cc = (idx >> 2) % 36;
      int r = (idx >> 2) / 36;          // 0..21 (r>=20 is pad)
      int y = y0 - 2 + r, xx = cc - 2;
      const short* gp = zero16;
      if (r < 20 && y >= 0 && y < HP && xx >= 0 && xx < WP)
        gp = hg + (y * WP + xx) * OC + chunk * 32 + icq * 8;
      __builtin_amdgcn_global_load_lds(
          (const __attribute__((address_space(1))) void*)gp,
          (__attribute__((address_space(3))) void*)&hs[idx * 8], 16, 0, 0);
    }
    __syncthreads();  // compiler drains vmcnt before the barrier

    const short* hb0 = &hs[(4 * w) * RS2 + n * CS2 + q * 8];
    const short* an = wbase + (size_t)chunk * 32 + (size_t)n * OC + q * 8;

    for (int dx = 0; dx < 5; dx++) {
      // A-frags for taps (dy=0..4, this dx); dy=0 loaded first -> ready for j=0
      short8 Acur[5][4];
#pragma unroll
      for (int dy = 0; dy < 5; dy++)
#pragma unroll
        for (int oct = 0; oct < 4; oct++)
          Acur[dy][oct] =
              *(const short8*)(an + ((size_t)(dy * 5 + dx) * OC + oct * 16) * OC);
      const short* hp = hb0 + dx * CS2;
#pragma unroll
      for (int j = 0; j < 8; j++) {   // slab row sr = 4w + j, read ONCE
        short8 B0 = *(const short8*)(hp + j * RS2);
        short8 B1 = *(const short8*)(hp + j * RS2 + 16 * CS2);
#pragma unroll
        for (int dy = 0; dy < 5; dy++) {
          if (dy > j || dy + 3 < j) continue;   // out row rt = j-dy in [0,3]
          int rt = j - dy;
#pragma unroll
          for (int oct = 0; oct < 4; oct++) {
            acc[oct][rt * 2 + 0] = __builtin_amdgcn_mfma_f32_16x16x32_bf16(
                Acur[dy][oct], B0, acc[oct][rt * 2 + 0], 0, 0, 0);
            acc[oct][rt * 2 + 1] = __builtin_amdgcn_mfma_f32_16x16x32_bf16(
                Acur[dy][oct], B1, acc[oct][rt * 2 + 1], 0, 0, 0);
          }
        }
      }
    }
  }

  // epilogue: max over this wave's 128 px; D layout: col(px)=lane&15, row(oc)=q*4+reg
#pragma unroll
  for (int oct = 0; oct < 4; oct++) {
    f32x4 m = acc[oct][0];
#pragma unroll
    for (int pxt = 1; pxt < 8; pxt++)
#pragma unroll
      for (int r = 0; r < 4; r++) m[r] = fmaxf(m[r], acc[oct][pxt][r]);
#pragma unroll
    for (int mask = 1; mask <= 8; mask <<= 1)
#pragma unroll
      for (int r = 0; r < 4; r++) m[r] = fmaxf(m[r], __shfl_xor(m[r], mask, 64));
    if (n == 0) *(f32x4*)&sred[w][oct * 16 + q * 4] = m;
  }
  __syncthreads();
  if (t < 64) {
    float m = fmaxf(fmaxf(sred[0][t], sred[1][t]), fmaxf(sred[2][t], sred[3][t]));
    pfeat[((size_t)(l * BATCH + b) * 2 + half) * OC + t] = m;
  }
}

// ---------------- per-leaf 2-layer MLP; folds half-max + relu ----------------
__global__ __launch_bounds__(128) void k_mlp(
    const float* __restrict__ pfeat, const float* __restrict__ w1s,
    const float* __restrict__ b1s, const float* __restrict__ w2s,
    const float* __restrict__ b2s, float* __restrict__ logits) {
  __shared__ float fs[OC];
  __shared__ float hid[LW];
  int bid = blockIdx.x;
  int b = bid & 31;
  int l = bid >> 5;
  int t = threadIdx.x;
  if (t < OC) {
    const float* pf = pfeat + (size_t)(l * BATCH + b) * 2 * OC;
    fs[t] = fmaxf(fmaxf(pf[t], pf[OC + t]), 0.f);  // relu(global max)
  }
  __syncthreads();
  float h = b1s[l * LW + t];
  for (int c = 0; c < OC; c++)
    h = fmaf(fs[c], w1s[(l * OC + c) * LW + t], h);
  hid[t] = h;
  __syncthreads();
  if (t < OW) {
    float o = b2s[l * OW + t];
    for (int j = 0; j < LW; j++)
      o = fmaf(hid[j], w2s[(l * LW + j) * OW + t], o);
    logits[(size_t)(l * BATCH + b) * OW + t] = o;
  }
}

// ---------------- out[b,o] = sum_l mix[b,l] * logits[l,b,o]  (fp32 out) ----------------
__global__ __launch_bounds__(256) void k_combine(
    const float* __restrict__ logits, const float* __restrict__ mix,
    float* __restrict__ out) {
  int idx = blockIdx.x * 256 + threadIdx.x;
  if (idx >= BATCH * OW) return;
  int b = idx / OW, o = idx - b * OW;
  float s = 0.f;
#pragma unroll
  for (int l = 0; l < NL; l++)
    s = fmaf(mix[b * NL + l], logits[((size_t)l * BATCH + b) * OW + o], s);
  out[idx] = s;
}

extern "C" void kernel_launch(void* const* d_in, const int* in_sizes, int n_in,
                              void* d_out, int out_size, void* d_ws, size_t ws_size,
                              hipStream_t stream) {
  const float* x   = (const float*)d_in[0];
  const float* nw  = (const float*)d_in[1];
  const float* nb  = (const float*)d_in[2];
  const float* cw1 = (const float*)d_in[3];
  const float* cw2 = (const float*)d_in[4];
  const float* w1s = (const float*)d_in[5];
  const float* b1s = (const float*)d_in[6];
  const float* w2s = (const float*)d_in[7];
  const float* b2s = (const float*)d_in[8];
  float* out = (float*)d_out;

  char* ws = (char*)d_ws;
  short* h1t = (short*)ws;  // [l,b][px 1024][ic 64] bf16 = 67.1 MB
  size_t off = (size_t)NL * BATCH * HP * WP * OC * sizeof(short);
  short* wT = (short*)(ws + off); off += (size_t)NL * 25 * OC * OC * sizeof(short);
  short* wA = (short*)(ws + off); off += (size_t)NL * OC * 96 * sizeof(short);
  float* scores_p = (float*)(ws + off); off += 4 * BATCH * 4 * sizeof(float);
  float* mixp   = (float*)(ws + off); off += BATCH * NL * sizeof(float);
  float* pfeat  = (float*)(ws + off); off += (size_t)NL * BATCH * 2 * OC * sizeof(float);
  float* logits = (float*)(ws + off); off += (size_t)NL * BATCH * OW * sizeof(float);
  (void)ws_size; (void)in_sizes; (void)n_in; (void)out_size;

  k_scores<<<4 * BATCH * 4, 256, 0, stream>>>(x, nw, scores_p);
  k_mix<<<1, BATCH * NL, 0, stream>>>(scores_p, nb, mixp);
  k_prep<<<(98304 + 204800) / 256, 256, 0, stream>>>(cw1, cw2, wA, wT);
  k_conv1m<<<BATCH * 32, 256, 0, stream>>>(x, wA, h1t);
  k_conv2m<<<NL * BATCH * 2, 256, 0, stream>>>(h1t, wT, pfeat);
  k_mlp<<<NL * BATCH, 128, 0, stream>>>(pfeat, w1s, b1s, w2s, b2s, logits);
  k_combine<<<(BATCH * OW + 255) / 256, 256, 0, stream>>>(logits, mixp, out);
}

// Round 4
// 226.538 us; speedup vs baseline: 1.0109x; 1.0109x over previous
//
#include <hip/hip_runtime.h>
#include <hip/hip_bf16.h>

using bf16 = __hip_bfloat16;
typedef __attribute__((ext_vector_type(8))) short short8;   // 8 bf16 (4 VGPR)
typedef __attribute__((ext_vector_type(4))) short short4v;  // 4 bf16 (8 B)
typedef __attribute__((ext_vector_type(4))) float f32x4;

constexpr int BATCH = 32;
constexpr int INC = 3;
constexpr int OC = 64;
constexpr int HH = 64;
constexpr int WW = 64;
constexpr int KK = 5;
constexpr int HP = 32;
constexpr int WP = 32;
constexpr int NL = 16;
constexpr int LW = 128;
constexpr int OW = 100;

__device__ __forceinline__ short f2bs(float v) {
  bf16 h = __float2bfloat16(v);
  return *(short*)&h;
}

// 16B zero page: per-lane global source for halo/pad lanes of global_load_lds.
// Device globals are zero-initialized at module load.
__device__ alignas(16) short zero16[16];

// ---------------- routing scores (partial): conv(x, node_filter) -> 16-row-group max ------
// grid: 4 depths * 32 batch * 4 row-groups = 512 blocks, 256 threads
__global__ __launch_bounds__(256) void k_scores(
    const float* __restrict__ x, const float* __restrict__ nw,
    float* __restrict__ scores_p) {
  int bid = blockIdx.x;
  int d = bid & 3;
  int b = (bid >> 2) & 31;
  int g = bid >> 7;  // 0..3: rows 16g..16g+15
  int f = (2 << d) - 2;  // node filter index used at depth d: 0,2,6,14
  __shared__ float wsm[75];
  __shared__ float red[256];
  int t = threadIdx.x;
  if (t < 75) wsm[t] = nw[f * 75 + t];
  __syncthreads();
  float m = -3.0e38f;
  for (int p = g * 1024 + t; p < (g + 1) * 1024; p += 256) {
    int y = p >> 6, xx = p & 63;
    float s = 0.f;
    for (int ic = 0; ic < INC; ic++) {
      for (int ky = 0; ky < KK; ky++) {
        int yy = y + ky - 2;
        if (yy < 0 || yy >= HH) continue;
        const float* xr = x + ((b * INC + ic) * HH + yy) * WW;
        const float* wr = &wsm[(ic * KK + ky) * KK];
        for (int kx = 0; kx < KK; kx++) {
          int xc = xx + kx - 2;
          if (xc < 0 || xc >= WW) continue;
          s = fmaf(xr[xc], wr[kx], s);
        }
      }
    }
    m = fmaxf(m, s);
  }
  red[t] = m;
  __syncthreads();
  for (int s2 = 128; s2 > 0; s2 >>= 1) {
    if (t < s2) red[t] = fmaxf(red[t], red[t + s2]);
    __syncthreads();
  }
  if (t == 0) scores_p[(d * BATCH + b) * 4 + g] = red[0];
}

// ---------------- soft-routing mixture over the binary tree (folds 4 partial maxes) -------
__global__ void k_mix(const float* __restrict__ scores_p,
                      const float* __restrict__ nb, float* __restrict__ mix) {
  int t = threadIdx.x;
  int b = t >> 4, l = t & 15;
  float m = 1.f;
#pragma unroll
  for (int d = 0; d < 4; d++) {
    const float* sp = scores_p + (d * BATCH + b) * 4;
    float sc = fmaxf(fmaxf(sp[0], sp[1]), fmaxf(sp[2], sp[3]));
    int j = l >> (3 - d);
    int i = j >> 1;
    int bit = j & 1;
    float z = sc + nb[(1 << d) - 1 + i];
    float be = 1.f / (1.f + expf(-z));
    m *= bit ? be : (1.f - be);
  }
  mix[b * NL + l] = m;
}

// ---------------- merged weight prep ----------------
__global__ __launch_bounds__(256) void k_prep(
    const float* __restrict__ cw1, const float* __restrict__ cw2,
    short* __restrict__ wA, short* __restrict__ wT) {
  int idx = blockIdx.x * 256 + threadIdx.x;
  if (idx < 98304) {
    int k = idx % 96;
    int rem = idx / 96;  // l*64 + oc
    float v = (k < 75) ? cw1[(size_t)rem * 75 + k] : 0.f;
    wA[(size_t)rem * 96 + k] = f2bs(v);
  } else {
    int i2 = idx - 98304;  // < 204800
    int icq = i2 & 7;
    int oc = (i2 >> 3) & 63;
    int rem = i2 >> 9;  // l*25 + tap
    short8 v;
#pragma unroll
    for (int j = 0; j < 8; j++) {
      int ic = icq * 8 + j;
      int l = rem / 25, tap = rem % 25;
      v[j] = f2bs(cw2[((size_t)(l * OC + oc) * OC + ic) * 25 + tap]);
    }
    *(short8*)(wT + ((size_t)rem * OC + oc) * OC + icq * 8) = v;
  }
}

// ---------------- conv1 via im2col + MFMA + in-register maxpool/relu -> h1t ----------------
// (R8/R12 version verbatim — known-good on hardware)
__device__ __forceinline__ int slotbase(int col) {
  return col * 104 + 8 * ((-(col >> 1)) & 7);
}

__global__ __launch_bounds__(256) void k_conv1m(
    const float* __restrict__ x, const short* __restrict__ wA,
    short* __restrict__ h1t) {
  constexpr int BSZ = 64 * 104 + 64;
  constexpr int OTS = 72;
  __shared__ alignas(16) short Bm[2 * BSZ];
  __shared__ alignas(16) short ot[32 * OTS];
  int bid = blockIdx.x;
  int py = bid & 31;
  int b = bid >> 5;
  int t = threadIdx.x;
  int w = t >> 6, lane = t & 63;
  int n = lane & 15, q = lane >> 4;

  for (int i = t; i < BSZ; i += 256) ((int*)Bm)[i] = 0;
  __syncthreads();
  for (int i = t; i < 1200; i += 256) {
    int cg = i & 7;
    int kk = (i >> 3) % 75;
    int dy = (i >> 3) / 75;
    int ic = kk / 25, r25 = kk % 25;
    int ky = r25 / 5, kx = r25 % 5;
    int y = 2 * py + dy + ky - 2;
    const float* xr = x + ((size_t)(b * INC + ic) * HH + y) * WW;
    short* dst = Bm + dy * BSZ;
#pragma unroll
    for (int c8 = 0; c8 < 8; c8++) {
      int c = cg * 8 + c8;
      int cx = c + kx - 2;
      float v = 0.f;
      if (y >= 0 && y < HH && cx >= 0 && cx < WW) v = xr[cx];
      dst[slotbase(c) + kk] = f2bs(v);
    }
  }
  __syncthreads();

  short8 Acur[3], Anx[3];
#pragma unroll
  for (int ks = 0; ks < 3; ks++)
    Anx[ks] = *(const short8*)(wA + ((size_t)(w * 16 + n) * 96) + ks * 32 + q * 8);

  for (int l = 0; l < NL; l++) {
#pragma unroll
    for (int ks = 0; ks < 3; ks++) Acur[ks] = Anx[ks];
    if (l < NL - 1) {
#pragma unroll
      for (int ks = 0; ks < 3; ks++)
        Anx[ks] = *(const short8*)(wA + ((size_t)((l + 1) * OC + w * 16 + n) * 96) +
                                   ks * 32 + q * 8);
    }
    f32x4 acc[2][2][2];  // [dy][dx][half]
#pragma unroll
    for (int dy = 0; dy < 2; dy++)
#pragma unroll
      for (int dx = 0; dx < 2; dx++)
#pragma unroll
        for (int h = 0; h < 2; h++) acc[dy][dx][h] = f32x4{0.f, 0.f, 0.f, 0.f};

#pragma unroll
    for (int dy = 0; dy < 2; dy++)
#pragma unroll
      for (int dx = 0; dx < 2; dx++)
#pragma unroll
        for (int h = 0; h < 2; h++) {
          int col = 2 * (h * 16 + n) + dx;
          const short* bp = Bm + dy * BSZ + slotbase(col);
#pragma unroll
          for (int ks = 0; ks < 3; ks++) {
            short8 Bf = *(const short8*)(bp + ks * 32 + q * 8);
            acc[dy][dx][h] = __builtin_amdgcn_mfma_f32_16x16x32_bf16(
                Acur[ks], Bf, acc[dy][dx][h], 0, 0, 0);
          }
        }

#pragma unroll
    for (int h = 0; h < 2; h++) {
      short4v sv;
#pragma unroll
      for (int r = 0; r < 4; r++) {
        float v = fmaxf(fmaxf(acc[0][0][h][r], acc[0][1][h][r]),
                        fmaxf(acc[1][0][h][r], acc[1][1][h][r]));
        sv[r] = f2bs(fmaxf(v, 0.f));
      }
      *(short4v*)(&ot[(h * 16 + n) * OTS + w * 16 + q * 4]) = sv;
    }
    __syncthreads();
    {
      int px = t >> 3, seg = t & 7;
      short8 v = *(const short8*)(&ot[px * OTS + seg * 8]);
      *(short8*)(h1t + ((size_t)(l * BATCH + b) * (HP * WP) + py * WP + px) * OC +
                 seg * 8) = v;
    }
    __syncthreads();
  }
}

// ---------------- conv2 via MFMA implicit GEMM + spatial max -> pfeat ----------------
// R16: dy-fold with INVERTED register allocation vs R15 (which spilled: 37 MB scratch).
// Hold the wave's 16 B-fragments (8 slab rows x 2 col-halves, 64 VGPR) in registers
// per (chunk,dx); loop dy with only the current tap's 4 A-frags (16 VGPR) live.
// Same B-read reduction as R15 (640/block vs 1600 baseline), fits 128 arch VGPRs.
// Staging stays global_load_lds width=16 (linear LDS, zero-page halo).
__global__ __launch_bounds__(256, 2) void k_conv2m(
    const short* __restrict__ h1t, const short* __restrict__ wT,
    float* __restrict__ pfeat) {
  constexpr int CS2 = 32;          // shorts per col slot (64 B, no pad: linear)
  constexpr int RS2 = 36 * CS2;    // 1152 shorts = 2304 B per slab row
  __shared__ alignas(16) short hs[3072 * 8];  // 49152 B (20*2304=46080 used + pad)
  __shared__ alignas(16) float sred[4][64];
  int bid = blockIdx.x;
  int half = bid & 1;
  int b = (bid >> 1) & 31;
  int l = bid >> 6;
  int t = threadIdx.x;
  int w = t >> 6, lane = t & 63;
  int n = lane & 15, q = lane >> 4;
  int y0 = half * 16;
  const short* hg = h1t + (size_t)(l * BATCH + b) * (HP * WP) * OC;
  const short* wbase = wT + (size_t)l * 25 * OC * OC;

  f32x4 acc[4][8];  // [octile][pxt = rt*2 + colhalf], rt = local out row 0..3
#pragma unroll
  for (int i = 0; i < 4; i++)
#pragma unroll
    for (int j = 0; j < 8; j++) acc[i][j] = f32x4{0.f, 0.f, 0.f, 0.f};

  for (int chunk = 0; chunk < 2; chunk++) {
    __syncthreads();  // protect hs from previous chunk's readers
    // stage: 12 uniform iters x 256 thr = 3072 x 16B (2880 real + pad -> zero page)
#pragma unroll
    for (int i = 0; i < 12; i++) {
      int idx = i * 256 + t;            // 0..3071
      int icq = idx & 3;
      int cc = (idx >> 2) % 36;
      int r = (idx >> 2) / 36;          // 0..21 (r>=20 is pad)
      int y = y0 - 2 + r, xx = cc - 2;
      const short* gp = zero16;
      if (r < 20 && y >= 0 && y < HP && xx >= 0 && xx < WP)
        gp = hg + (y * WP + xx) * OC + chunk * 32 + icq * 8;
      __builtin_amdgcn_global_load_lds(
          (const __attribute__((address_space(1))) void*)gp,
          (__attribute__((address_space(3))) void*)&hs[idx * 8], 16, 0, 0);
    }
    __syncthreads();  // compiler drains vmcnt before the barrier

    const short* hb0 = &hs[(4 * w) * RS2 + n * CS2 + q * 8];
    const short* an = wbase + (size_t)chunk * 32 + (size_t)n * OC + q * 8;

    for (int dx = 0; dx < 5; dx++) {
      const short* hp = hb0 + dx * CS2;
      // bulk-read the wave's 16 B-fragments ONCE for this (chunk, dx)
      short8 Bf[8][2];
#pragma unroll
      for (int j = 0; j < 8; j++) {
        Bf[j][0] = *(const short8*)(hp + j * RS2);
        Bf[j][1] = *(const short8*)(hp + j * RS2 + 16 * CS2);
      }
#pragma unroll
      for (int dy = 0; dy < 5; dy++) {
        short8 Af[4];
#pragma unroll
        for (int oct = 0; oct < 4; oct++)
          Af[oct] = *(const short8*)(
              an + ((size_t)((dy * 5 + dx) * OC + oct * 16)) * OC);
#pragma unroll
        for (int rt = 0; rt < 4; rt++) {
          int j = rt + dy;  // slab row 4w + j feeds out row 4w + rt via tap dy
#pragma unroll
          for (int oct = 0; oct < 4; oct++) {
            acc[oct][rt * 2 + 0] = __builtin_amdgcn_mfma_f32_16x16x32_bf16(
                Af[oct], Bf[j][0], acc[oct][rt * 2 + 0], 0, 0, 0);
            acc[oct][rt * 2 + 1] = __builtin_amdgcn_mfma_f32_16x16x32_bf16(
                Af[oct], Bf[j][1], acc[oct][rt * 2 + 1], 0, 0, 0);
          }
        }
      }
    }
  }

  // epilogue: max over this wave's 128 px; D layout: col(px)=lane&15, row(oc)=q*4+reg
#pragma unroll
  for (int oct = 0; oct < 4; oct++) {
    f32x4 m = acc[oct][0];
#pragma unroll
    for (int pxt = 1; pxt < 8; pxt++)
#pragma unroll
      for (int r = 0; r < 4; r++) m[r] = fmaxf(m[r], acc[oct][pxt][r]);
#pragma unroll
    for (int mask = 1; mask <= 8; mask <<= 1)
#pragma unroll
      for (int r = 0; r < 4; r++) m[r] = fmaxf(m[r], __shfl_xor(m[r], mask, 64));
    if (n == 0) *(f32x4*)&sred[w][oct * 16 + q * 4] = m;
  }
  __syncthreads();
  if (t < 64) {
    float m = fmaxf(fmaxf(sred[0][t], sred[1][t]), fmaxf(sred[2][t], sred[3][t]));
    pfeat[((size_t)(l * BATCH + b) * 2 + half) * OC + t] = m;
  }
}

// ---------------- per-leaf 2-layer MLP; folds half-max + relu ----------------
__global__ __launch_bounds__(128) void k_mlp(
    const float* __restrict__ pfeat, const float* __restrict__ w1s,
    const float* __restrict__ b1s, const float* __restrict__ w2s,
    const float* __restrict__ b2s, float* __restrict__ logits) {
  __shared__ float fs[OC];
  __shared__ float hid[LW];
  int bid = blockIdx.x;
  int b = bid & 31;
  int l = bid >> 5;
  int t = threadIdx.x;
  if (t < OC) {
    const float* pf = pfeat + (size_t)(l * BATCH + b) * 2 * OC;
    fs[t] = fmaxf(fmaxf(pf[t], pf[OC + t]), 0.f);  // relu(global max)
  }
  __syncthreads();
  float h = b1s[l * LW + t];
  for (int c = 0; c < OC; c++)
    h = fmaf(fs[c], w1s[(l * OC + c) * LW + t], h);
  hid[t] = h;
  __syncthreads();
  if (t < OW) {
    float o = b2s[l * OW + t];
    for (int j = 0; j < LW; j++)
      o = fmaf(hid[j], w2s[(l * LW + j) * OW + t], o);
    logits[(size_t)(l * BATCH + b) * OW + t] = o;
  }
}

// ---------------- out[b,o] = sum_l mix[b,l] * logits[l,b,o]  (fp32 out) ----------------
__global__ __launch_bounds__(256) void k_combine(
    const float* __restrict__ logits, const float* __restrict__ mix,
    float* __restrict__ out) {
  int idx = blockIdx.x * 256 + threadIdx.x;
  if (idx >= BATCH * OW) return;
  int b = idx / OW, o = idx - b * OW;
  float s = 0.f;
#pragma unroll
  for (int l = 0; l < NL; l++)
    s = fmaf(mix[b * NL + l], logits[((size_t)l * BATCH + b) * OW + o], s);
  out[idx] = s;
}

extern "C" void kernel_launch(void* const* d_in, const int* in_sizes, int n_in,
                              void* d_out, int out_size, void* d_ws, size_t ws_size,
                              hipStream_t stream) {
  const float* x   = (const float*)d_in[0];
  const float* nw  = (const float*)d_in[1];
  const float* nb  = (const float*)d_in[2];
  const float* cw1 = (const float*)d_in[3];
  const float* cw2 = (const float*)d_in[4];
  const float* w1s = (const float*)d_in[5];
  const float* b1s = (const float*)d_in[6];
  const float* w2s = (const float*)d_in[7];
  const float* b2s = (const float*)d_in[8];
  float* out = (float*)d_out;

  char* ws = (char*)d_ws;
  short* h1t = (short*)ws;  // [l,b][px 1024][ic 64] bf16 = 67.1 MB
  size_t off = (size_t)NL * BATCH * HP * WP * OC * sizeof(short);
  short* wT = (short*)(ws + off); off += (size_t)NL * 25 * OC * OC * sizeof(short);
  short* wA = (short*)(ws + off); off += (size_t)NL * OC * 96 * sizeof(short);
  float* scores_p = (float*)(ws + off); off += 4 * BATCH * 4 * sizeof(float);
  float* mixp   = (float*)(ws + off); off += BATCH * NL * sizeof(float);
  float* pfeat  = (float*)(ws + off); off += (size_t)NL * BATCH * 2 * OC * sizeof(float);
  float* logits = (float*)(ws + off); off += (size_t)NL * BATCH * OW * sizeof(float);
  (void)ws_size; (void)in_sizes; (void)n_in; (void)out_size;

  k_scores<<<4 * BATCH * 4, 256, 0, stream>>>(x, nw, scores_p);
  k_mix<<<1, BATCH * NL, 0, stream>>>(scores_p, nb, mixp);
  k_prep<<<(98304 + 204800) / 256, 256, 0, stream>>>(cw1, cw2, wA, wT);
  k_conv1m<<<BATCH * 32, 256, 0, stream>>>(x, wA, h1t);
  k_conv2m<<<NL * BATCH * 2, 256, 0, stream>>>(h1t, wT, pfeat);
  k_mlp<<<NL * BATCH, 128, 0, stream>>>(pfeat, w1s, b1s, w2s, b2s, logits);
  k_combine<<<(BATCH * OW + 255) / 256, 256, 0, stream>>>(logits, mixp, out);
}